// Round 7
// baseline (755.781 us; speedup 1.0000x reference)
//
#include <hip/hip_runtime.h>
#include <hip/hip_bf16.h>
#include <stdint.h>

using bf16 = __hip_bfloat16;
typedef short s16x8 __attribute__((ext_vector_type(8)));
typedef float f32x4 __attribute__((ext_vector_type(4)));

#define NB 4
#define NS 1024
#define ND 768
#define NH 12
#define NE 8
#define NHID 3072
#define NTOK 4096
#define NASSIGN 8192
#define MAXCH 72               // sum ceil(counts[e]/128) <= 64 + 8
#define MAXSLOT (MAXCH * 128)  // 9216

__device__ __forceinline__ float bf2f(bf16 v){ return __bfloat162float(v); }
__device__ __forceinline__ bf16 f2bf(float v){ return __float2bfloat16(v); }

__device__ __forceinline__ void gload_lds16(const bf16* g, bf16* l){
  __builtin_amdgcn_global_load_lds((const __attribute__((address_space(1))) void*)g,
                                   (__attribute__((address_space(3))) void*)l, 16, 0, 0);
}

// ---------------- transpose + fp32->bf16 convert, 64x64 tile, 16B loads/stores
__device__ __forceinline__ void transpose64_body(const float* __restrict__ src,
                                                 bf16* __restrict__ dst,
                                                 int K, int N, int n0, int k0, int t){
  __shared__ float tile[64][65];
  int kr = t >> 4, c4 = (t & 15) * 4;
  #pragma unroll
  for (int i = 0; i < 4; i++){
    int k = kr + i * 16;
    float4 v = *(const float4*)(src + (size_t)(k0 + k) * N + n0 + c4);
    tile[k][c4]     = v.x;
    tile[k][c4 + 1] = v.y;
    tile[k][c4 + 2] = v.z;
    tile[k][c4 + 3] = v.w;
  }
  __syncthreads();
  int nr = t >> 3, k8 = (t & 7) * 8;
  #pragma unroll
  for (int i = 0; i < 2; i++){
    int n = nr + i * 32;
    short vv[8];
    #pragma unroll
    for (int j = 0; j < 8; j++){
      bf16 x = f2bf(tile[k8 + j][n]);
      vv[j] = *(short*)&x;
    }
    *(s16x8*)(dst + (size_t)(n0 + n) * K + k0 + k8) = *(s16x8*)vv;
  }
}

__global__ void transpose_convert_kernel(const float* __restrict__ src, bf16* __restrict__ dst,
                                         int K, int N){
  int bz = blockIdx.z;
  transpose64_body(src + (size_t)bz * K * N, dst + (size_t)bz * N * K,
                   K, N, blockIdx.x * 64, blockIdx.y * 64, threadIdx.x);
}

// four 768x768 fp32->bf16 transposes in one dispatch (wq,wk,wv,wo -> contiguous dst)
struct Ptr4 { const float* p0; const float* p1; const float* p2; const float* p3; };
__global__ void transpose4_kernel(Ptr4 s4, bf16* __restrict__ dst){
  int z = blockIdx.z;
  const float* src = (z == 0) ? s4.p0 : (z == 1) ? s4.p1 : (z == 2) ? s4.p2 : s4.p3;
  transpose64_body(src, dst + (size_t)z * 768 * 768,
                   768, 768, blockIdx.x * 64, blockIdx.y * 64, threadIdx.x);
}

// ---------------- concat 3 bias vectors [768] -> [2304]
__global__ void concat3_kernel(const float* __restrict__ a, const float* __restrict__ b,
                               const float* __restrict__ c, float* __restrict__ out){
  int i = blockIdx.x * 256 + threadIdx.x;
  if (i >= 3 * ND) return;
  float v = (i < ND) ? a[i] : (i < 2 * ND ? b[i - ND] : c[i - 2 * ND]);
  out[i] = v;
}

// ---------------- LayerNorm row kernel (768 per row, 256 threads)
template<bool OF, bool OB>
__global__ void ln_kernel(const float* __restrict__ in, const float* __restrict__ g,
                          const float* __restrict__ bb, float* __restrict__ of,
                          bf16* __restrict__ ob){
  int row = blockIdx.x, t = threadIdx.x;
  const float* x = in + (size_t)row * ND;
  float v[3]; float s = 0.f, sq = 0.f;
  #pragma unroll
  for (int i = 0; i < 3; i++){ v[i] = x[t + i * 256]; s += v[i]; sq += v[i] * v[i]; }
  __shared__ float rs[4], rq[4];
  #pragma unroll
  for (int d = 32; d >= 1; d >>= 1){ s += __shfl_xor(s, d); sq += __shfl_xor(sq, d); }
  int w = t >> 6;
  if ((t & 63) == 0){ rs[w] = s; rq[w] = sq; }
  __syncthreads();
  s = rs[0] + rs[1] + rs[2] + rs[3];
  sq = rq[0] + rq[1] + rq[2] + rq[3];
  float mean = s * (1.f / ND);
  float var = sq * (1.f / ND) - mean * mean;
  float rstd = rsqrtf(var + 1e-5f);
  #pragma unroll
  for (int i = 0; i < 3; i++){
    int idx = t + i * 256;
    float y = (v[i] - mean) * rstd * g[idx] + bb[idx];
    if (OF) of[(size_t)row * ND + idx] = y;
    if (OB) ob[(size_t)row * ND + idx] = f2bf(y);
  }
}

// ---------------- GEMM (128x128, 4 waves): verified 2-buffer dbuf structure
template<int GROUP, bool GATHER, bool RELU, bool OBF, bool RESID, bool SEG, bool SPLITZ>
__global__ __launch_bounds__(256, 4)
void gemm_kernel(const bf16* __restrict__ A, int ldA,
                 const bf16* __restrict__ BtB,
                 const float* __restrict__ biasB,
                 void* __restrict__ Cv, int ldC,
                 const float* __restrict__ resid,
                 int N, int K, int ldB, size_t czstride,
                 const int* __restrict__ chunk_e, const int* __restrict__ tok){
  __shared__ __align__(16) bf16 sA[2][128 * 32];
  __shared__ __align__(16) bf16 sB[2][128 * 32];

  int t = threadIdx.x;
  int lane = t & 63, wv = t >> 6;
  int c0i = wv * 128 + lane;          // staging chunk id (and c0i+64)
  int r0  = c0i >> 2;                 // tile-local row of chunk0; chunk1 row = r0+16
  int kk  = (c0i & 3) * 8;
  int nt, cbase = 0, ks = 0;
  if (SPLITZ){
    int l = blockIdx.x, xcd = l & 7, slot = l >> 3;
    int grp = xcd + 8 * (slot / 6);   // 144 (chunk,ks) groups, 18 per XCD
    nt = slot % 6;
    cbase = grp % MAXCH;
    ks = grp / MAXCH;
  } else {
    nt = blockIdx.x;
  }
  int koff = ks * K;
  float* Cfs = (float*)Cv + (size_t)ks * czstride;
  int wm = (wv >> 1) * 64, wn = (wv & 1) * 64;
  int l16 = lane & 15, q4 = lane >> 4;
  int aoff[4], boff[4];
  #pragma unroll
  for (int mi = 0; mi < 4; mi++) aoff[mi] = (wm + mi * 16 + l16) * 32 + q4 * 8;
  #pragma unroll
  for (int ni = 0; ni < 4; ni++) boff[ni] = (wn + ni * 16 + l16) * 32 + q4 * 8;

  for (int g = 0; g < GROUP; g++){
    int c = SPLITZ ? cbase : blockIdx.y * GROUP + g;
    int e = 0;
    if (SEG){ e = chunk_e[c]; if (e < 0) break; }
    const bf16* Bt = SEG ? BtB + (size_t)e * N * ldB : BtB;
    const float* bias = SEG ? biasB + (size_t)e * N : biasB;
    size_t arow0, arow1;
    int m0 = c * 128 + r0, m1 = m0 + 16;
    if (GATHER){ arow0 = (size_t)tok[m0]; arow1 = (size_t)tok[m1]; }
    else       { arow0 = (size_t)m0;      arow1 = (size_t)m1; }
    const bf16* gA0 = A + arow0 * ldA + koff + kk;
    const bf16* gA1 = A + arow1 * ldA + koff + kk;
    const bf16* gB0 = Bt + (size_t)(nt * 128 + r0) * ldB + koff + kk;
    const bf16* gB1 = Bt + (size_t)(nt * 128 + r0 + 16) * ldB + koff + kk;

    if (g > 0) __syncthreads();  // protect LDS reuse across chunks

    f32x4 acc[4][4] = {};
    gload_lds16(gA0, &sA[0][(size_t)c0i * 8]);
    gload_lds16(gA1, &sA[0][(size_t)(c0i + 64) * 8]);
    gload_lds16(gB0, &sB[0][(size_t)c0i * 8]);
    gload_lds16(gB1, &sB[0][(size_t)(c0i + 64) * 8]);

    int nk = K >> 5;
    for (int ki = 0; ki < nk; ki++){
      int cur = ki & 1;
      __syncthreads();
      if (ki + 1 < nk){
        int nxt = cur ^ 1, off = (ki + 1) * 32;
        gload_lds16(gA0 + off, &sA[nxt][(size_t)c0i * 8]);
        gload_lds16(gA1 + off, &sA[nxt][(size_t)(c0i + 64) * 8]);
        gload_lds16(gB0 + off, &sB[nxt][(size_t)c0i * 8]);
        gload_lds16(gB1 + off, &sB[nxt][(size_t)(c0i + 64) * 8]);
      }
      s16x8 af[4], bfr[4];
      #pragma unroll
      for (int mi = 0; mi < 4; mi++) af[mi] = *(const s16x8*)(&sA[cur][0] + aoff[mi]);
      #pragma unroll
      for (int ni = 0; ni < 4; ni++) bfr[ni] = *(const s16x8*)(&sB[cur][0] + boff[ni]);
      #pragma unroll
      for (int mi = 0; mi < 4; mi++)
        #pragma unroll
        for (int ni = 0; ni < 4; ni++)
          acc[mi][ni] = __builtin_amdgcn_mfma_f32_16x16x32_bf16(af[mi], bfr[ni], acc[mi][ni], 0, 0, 0);
    }

    #pragma unroll
    for (int mi = 0; mi < 4; mi++){
      #pragma unroll
      for (int ni = 0; ni < 4; ni++){
        int col = nt * 128 + wn + ni * 16 + l16;
        float bv = (!SPLITZ || ks == 0) ? bias[col] : 0.f;
        #pragma unroll
        for (int r = 0; r < 4; r++){
          size_t crow = (size_t)(c * 128 + wm + mi * 16 + q4 * 4 + r);
          float v = acc[mi][ni][r] + bv;
          if (RELU) v = fmaxf(v, 0.f);
          if (RESID) v += resid[crow * ldC + col];
          if (OBF) ((bf16*)Cv)[crow * ldC + col] = f2bf(v);
          else     Cfs[crow * ldC + col] = v;
        }
      }
    }
  }
}

// ---------------- GEMM wide (128x256, 8 waves, 512 threads): same 2-phase sync,
// B-traffic per output halved, 24 waves/CU (3 blocks x 8). Per-wave math code
// identical to gemm_kernel (acc 4x4 of 16x16 fragments over a 64x64 subtile).
template<bool GATHER, bool RELU, bool OBF, bool SEG>
__global__ __launch_bounds__(512, 6)
void gemm_wide_kernel(const bf16* __restrict__ A, int ldA,
                      const bf16* __restrict__ BtB,
                      const float* __restrict__ biasB,
                      void* __restrict__ Cv, int ldC,
                      int N, int K,
                      const int* __restrict__ chunk_e, const int* __restrict__ tok){
  __shared__ __align__(16) bf16 sA[2][128 * 32];
  __shared__ __align__(16) bf16 sB[2][256 * 32];

  int t = threadIdx.x;
  int lane = t & 63, wv = t >> 6;          // wv 0..7
  int r0 = t >> 2;                         // 0..127
  int kk = (t & 3) * 8;
  int nt = blockIdx.x, c = blockIdx.y;
  int e = 0;
  if (SEG){ e = chunk_e[c]; if (e < 0) return; }
  const bf16* Bt = SEG ? BtB + (size_t)e * N * K : BtB;
  const float* bias = SEG ? biasB + (size_t)e * N : biasB;
  size_t arow = GATHER ? (size_t)tok[c * 128 + r0] : (size_t)(c * 128 + r0);
  const bf16* gA  = A + arow * ldA + kk;
  const bf16* gB0 = Bt + (size_t)(nt * 256 + r0) * K + kk;
  const bf16* gB1 = gB0 + (size_t)128 * K;

  int wm = (wv >> 2) * 64, wn = (wv & 3) * 64;
  int l16 = lane & 15, q4 = lane >> 4;
  int aoff[4], boff[4];
  #pragma unroll
  for (int mi = 0; mi < 4; mi++) aoff[mi] = (wm + mi * 16 + l16) * 32 + q4 * 8;
  #pragma unroll
  for (int ni = 0; ni < 4; ni++) boff[ni] = (wn + ni * 16 + l16) * 32 + q4 * 8;

  f32x4 acc[4][4] = {};
  gload_lds16(gA,  &sA[0][(size_t)t * 8]);
  gload_lds16(gB0, &sB[0][(size_t)t * 8]);
  gload_lds16(gB1, &sB[0][(size_t)(t + 512) * 8]);

  int nk = K >> 5;
  for (int ki = 0; ki < nk; ki++){
    int cur = ki & 1;
    __syncthreads();
    if (ki + 1 < nk){
      int nxt = cur ^ 1, off = (ki + 1) * 32;
      gload_lds16(gA  + off, &sA[nxt][(size_t)t * 8]);
      gload_lds16(gB0 + off, &sB[nxt][(size_t)t * 8]);
      gload_lds16(gB1 + off, &sB[nxt][(size_t)(t + 512) * 8]);
    }
    s16x8 af[4], bfr[4];
    #pragma unroll
    for (int mi = 0; mi < 4; mi++) af[mi] = *(const s16x8*)(&sA[cur][0] + aoff[mi]);
    #pragma unroll
    for (int ni = 0; ni < 4; ni++) bfr[ni] = *(const s16x8*)(&sB[cur][0] + boff[ni]);
    #pragma unroll
    for (int mi = 0; mi < 4; mi++)
      #pragma unroll
      for (int ni = 0; ni < 4; ni++)
        acc[mi][ni] = __builtin_amdgcn_mfma_f32_16x16x32_bf16(af[mi], bfr[ni], acc[mi][ni], 0, 0, 0);
  }

  #pragma unroll
  for (int mi = 0; mi < 4; mi++){
    #pragma unroll
    for (int ni = 0; ni < 4; ni++){
      int col = nt * 256 + wn + ni * 16 + l16;
      float bv = bias[col];
      #pragma unroll
      for (int r = 0; r < 4; r++){
        size_t crow = (size_t)(c * 128 + wm + mi * 16 + q4 * 4 + r);
        float v = acc[mi][ni][r] + bv;
        if (RELU) v = fmaxf(v, 0.f);
        if (OBF) ((bf16*)Cv)[crow * ldC + col] = f2bf(v);
        else     ((float*)Cv)[crow * ldC + col] = v;
      }
    }
  }
}

// ---------------- V transpose: qkv v-cols [b,s,h,d] -> vT [b,h,d,s] (bf16)
__global__ void vtrans_kernel(const bf16* __restrict__ qkv, bf16* __restrict__ vT){
  __shared__ bf16 tile[64][65];
  int bh = blockIdx.z; int b = bh / NH, h = bh % NH;
  int s0 = blockIdx.x * 64;
  int t = threadIdx.x;
  int sr = t >> 3, d8 = (t & 7) * 8;
  #pragma unroll
  for (int i = 0; i < 2; i++){
    int s = sr + i * 32;
    s16x8 v = *(const s16x8*)(qkv + (size_t)(b * NS + s0 + s) * 2304 + 1536 + h * 64 + d8);
    #pragma unroll
    for (int j = 0; j < 8; j++) tile[d8 + j][s] = ((bf16*)&v)[j];
  }
  __syncthreads();
  int dr = t >> 3, s8 = (t & 7) * 8;
  #pragma unroll
  for (int i = 0; i < 2; i++){
    int d = dr + i * 32;
    short vv[8];
    #pragma unroll
    for (int j = 0; j < 8; j++){ bf16 x = tile[d][s8 + j]; vv[j] = *(short*)&x; }
    *(s16x8*)(vT + ((size_t)bh * 64 + d) * NS + s0 + s8) = *(s16x8*)vv;
  }
}

// ---------------- flash attention v3 (unchanged)
#define SPAD 72
__global__ __launch_bounds__(256, 3)
void flash_attn_kernel(const bf16* __restrict__ qkv, const bf16* __restrict__ vT,
                       bf16* __restrict__ ctx){
  __shared__ __align__(16) bf16 sK[2][64 * 64];
  __shared__ __align__(16) bf16 sV[2][64 * 64];
  __shared__ __align__(16) bf16 sP[4][16 * SPAD];
  int id = blockIdx.x;
  int bh = id % 48;
  int qt = 15 - (id / 48);
  int b = bh / NH, h = bh % NH;
  int t = threadIdx.x, lane = t & 63, wv = t >> 6;
  int l16 = lane & 15, q4 = lane >> 4;
  int q0 = qt * 64 + wv * 16;
  const size_t ldq = 2304;
  const bf16* qbase = qkv + (size_t)(b * NS) * ldq + h * 64;
  const bf16* kbase = qbase + 768;
  const bf16* vtb = vT + (size_t)bh * 64 * NS;
  bf16* sPw = &sP[wv][0];
  const f32x4 fzero = {0.f, 0.f, 0.f, 0.f};

  s16x8 qf[2];
  #pragma unroll
  for (int kh = 0; kh < 2; kh++)
    qf[kh] = *(const s16x8*)(qbase + (size_t)(q0 + l16) * ldq + kh * 32 + q4 * 8);

  f32x4 O[4] = {};
  float ms[4], ls[4];
  #pragma unroll
  for (int r = 0; r < 4; r++){ ms[r] = -1e30f; ls[r] = 0.f; }

  int sub = lane >> 3, rawc = lane & 7;
  auto stage = [&](int buf, int key0){
    #pragma unroll
    for (int i = 0; i < 2; i++){
      int rk = wv * 8 + sub + i * 32;          // key row (K) / dh row (V)
      int cs = (rawc ^ (rk & 7)) * 8;          // swizzled source col (elems)
      gload_lds16(kbase + (size_t)(key0 + rk) * ldq + cs, &sK[buf][wv * 512 + i * 2048]);
      gload_lds16(vtb + (size_t)rk * NS + key0 + cs,      &sV[buf][wv * 512 + i * 2048]);
    }
  };

  int ntiles = qt + 1;
  stage(0, 0);
  for (int ti = 0; ti < ntiles; ti++){
    int cur = ti & 1, key0 = ti * 64;
    __syncthreads();                       // drains own staging loads + barrier
    if (ti + 1 < ntiles) stage(cur ^ 1, (ti + 1) * 64);
    if (key0 <= q0 + 15){
      const bf16* sKc = &sK[cur][0];
      const bf16* sVc = &sV[cur][0];
      s16x8 kf[4][2], vf[4][2];
      #pragma unroll
      for (int ni = 0; ni < 4; ni++){
        int krow = ni * 16 + l16;
        #pragma unroll
        for (int kh = 0; kh < 2; kh++)
          kf[ni][kh] = *(const s16x8*)(sKc + krow * 64 + (((kh * 4 + q4) ^ (krow & 7)) * 8));
      }
      #pragma unroll
      for (int dt = 0; dt < 4; dt++){
        int vrow = dt * 16 + l16;
        #pragma unroll
        for (int kh = 0; kh < 2; kh++)
          vf[dt][kh] = *(const s16x8*)(sVc + vrow * 64 + (((kh * 4 + q4) ^ (vrow & 7)) * 8));
      }
      f32x4 Sf[4];
      #pragma unroll
      for (int ni = 0; ni < 4; ni++){
        Sf[ni] = __builtin_amdgcn_mfma_f32_16x16x32_bf16(qf[0], kf[ni][0], fzero, 0, 0, 0);
        Sf[ni] = __builtin_amdgcn_mfma_f32_16x16x32_bf16(qf[1], kf[ni][1], Sf[ni], 0, 0, 0);
      }
      bool need_mask = (key0 + 63 >= q0);  // wave-uniform
      #pragma unroll
      for (int r = 0; r < 4; r++){
        int qrow = q0 + q4 * 4 + r;
        float sv[4];
        #pragma unroll
        for (int ni = 0; ni < 4; ni++){
          sv[ni] = Sf[ni][r] * 0.125f;
          if (need_mask && (key0 + ni * 16 + l16 > qrow)) sv[ni] = -1e30f;
        }
        float mx = fmaxf(fmaxf(sv[0], sv[1]), fmaxf(sv[2], sv[3]));
        #pragma unroll
        for (int d = 8; d >= 1; d >>= 1) mx = fmaxf(mx, __shfl_xor(mx, d));
        float mnew = fmaxf(ms[r], mx);
        float alpha = __expf(ms[r] - mnew);
        float p[4], psum = 0.f;
        #pragma unroll
        for (int ni = 0; ni < 4; ni++){ p[ni] = __expf(sv[ni] - mnew); psum += p[ni]; }
        #pragma unroll
        for (int d = 8; d >= 1; d >>= 1) psum += __shfl_xor(psum, d);
        ls[r] = ls[r] * alpha + psum;
        ms[r] = mnew;
        #pragma unroll
        for (int dt = 0; dt < 4; dt++) O[dt][r] *= alpha;
        int prow = q4 * 4 + r;
        #pragma unroll
        for (int ni = 0; ni < 4; ni++)
          sPw[prow * SPAD + ni * 16 + l16] = f2bf(p[ni]);
      }
      s16x8 pf[2];
      #pragma unroll
      for (int kh = 0; kh < 2; kh++)
        pf[kh] = *(const s16x8*)(sPw + l16 * SPAD + kh * 32 + q4 * 8);
      #pragma unroll
      for (int dt = 0; dt < 4; dt++){
        O[dt] = __builtin_amdgcn_mfma_f32_16x16x32_bf16(pf[0], vf[dt][0], O[dt], 0, 0, 0);
        O[dt] = __builtin_amdgcn_mfma_f32_16x16x32_bf16(pf[1], vf[dt][1], O[dt], 0, 0, 0);
      }
    }
  }

  #pragma unroll
  for (int r = 0; r < 4; r++){
    float inv = 1.f / ls[r];
    int qrow = q0 + q4 * 4 + r;
    #pragma unroll
    for (int dt = 0; dt < 4; dt++)
      ctx[(size_t)(b * NS + qrow) * ND + h * 64 + dt * 16 + l16] = f2bf(O[dt][r] * inv);
  }
}

// ---------------- gate v2: 128 blocks x 32 tokens; LDS count aggregation
__global__ __launch_bounds__(256)
void gate_kernel(const float* __restrict__ h, const float* __restrict__ gw,
                 const float* __restrict__ gb, int* __restrict__ ridx,
                 float* __restrict__ rw, int* __restrict__ counts){
  __shared__ float sgw[NE * ND];   // transposed: sgw[e*ND+i] -> stride-1 reads
  __shared__ int scnt[NE];
  int t = threadIdx.x;
  if (t < NE) scnt[t] = 0;
  for (int idx = t; idx < ND * NE; idx += 256){
    int i = idx >> 3, e = idx & 7;
    sgw[e * ND + i] = gw[idx];
  }
  __syncthreads();
  int lane = t & 63, wv = t >> 6;
  for (int it = 0; it < 8; it++){
    int tok = blockIdx.x * 32 + it * 4 + wv;
    const float* hr = h + (size_t)tok * ND;
    float acc[NE] = {};
    #pragma unroll
    for (int ii = 0; ii < 12; ii++){
      int i = lane + ii * 64;
      float hv = hr[i];
      #pragma unroll
      for (int e = 0; e < NE; e++) acc[e] += hv * sgw[e * ND + i];
    }
    #pragma unroll
    for (int e = 0; e < NE; e++)
      #pragma unroll
      for (int d = 32; d >= 1; d >>= 1) acc[e] += __shfl_xor(acc[e], d);
    if (lane == 0){
      float v0 = -1e30f, v1 = -1e30f; int i0 = 0, i1 = 0;
      #pragma unroll
      for (int e = 0; e < NE; e++){
        float v = acc[e] + gb[e];
        if (v > v0){ v1 = v0; i1 = i0; v0 = v; i0 = e; }
        else if (v > v1){ v1 = v; i1 = e; }
      }
      float w0 = 1.f / (1.f + __expf(v1 - v0));
      ridx[tok * 2] = i0; ridx[tok * 2 + 1] = i1;
      rw[tok * 2] = w0;  rw[tok * 2 + 1] = 1.f - w0;
      atomicAdd(&scnt[i0], 1);
      atomicAdd(&scnt[i1], 1);
    }
  }
  __syncthreads();
  if (t < NE) atomicAdd(&counts[t], scnt[t]);
}

// scan: padded (128-aligned) expert offsets + chunk->expert map + tok_list prefill
__global__ void scan_kernel(const int* __restrict__ counts, int* __restrict__ poff,
                            int* __restrict__ chunk_e, int* __restrict__ tok_list){
  int t = threadIdx.x;
  for (int i = t; i < MAXSLOT; i += 256) tok_list[i] = 0;
  if (t == 0){
    int s = 0, c = 0;
    for (int e = 0; e < NE; e++){
      poff[e] = s;
      int nch = (counts[e] + 127) >> 7;
      for (int i = 0; i < nch; i++) chunk_e[c++] = e;
      s += nch << 7;
    }
    for (; c < MAXCH; c++) chunk_e[c] = -1;
  }
}

// scatter v2: wave-aggregated atomics (1 atomic per expert per wave)
__global__ void scatter_kernel(const int* __restrict__ ridx, const int* __restrict__ poff,
                               int* __restrict__ cursor, int* __restrict__ tok_list,
                               int* __restrict__ slot_of){
  int tk = blockIdx.x * 256 + threadIdx.x;
  int lane = threadIdx.x & 63;
  int e = ridx[tk];
  unsigned long long lmask = (1ull << lane) - 1;  // bits below lane
  int slot = 0;
  #pragma unroll
  for (int ee = 0; ee < NE; ee++){
    unsigned long long mask = __ballot(e == ee);
    if (mask == 0ull) continue;
    int leader = __ffsll((unsigned long long)mask) - 1;
    int base = 0;
    if (lane == leader) base = atomicAdd(&cursor[ee], __popcll(mask));
    base = __shfl(base, leader);
    if (e == ee) slot = poff[ee] + base + __popcll(mask & lmask);
  }
  tok_list[slot] = tk >> 1;
  slot_of[tk] = slot;
}

// ---------------- combine: core = w0*(p0[s0]+p1[s0]) + w1*(p0[s1]+p1[s1]);
// out = attn_x + LN(h+core).  e2 partials are fp32 (split-K halves).
__global__ void combine_kernel(const float* __restrict__ e2p, const int* __restrict__ slot_of,
                               const float* __restrict__ rw, const float* __restrict__ hf,
                               const float* __restrict__ attn_x, const float* __restrict__ g,
                               const float* __restrict__ bb, float* __restrict__ out){
  int row = blockIdx.x, t = threadIdx.x;
  int sl0 = slot_of[row * 2], sl1 = slot_of[row * 2 + 1];
  float w0 = rw[row * 2], w1 = rw[row * 2 + 1];
  const float* r0a = e2p + (size_t)sl0 * ND;
  const float* r0b = r0a + (size_t)MAXSLOT * ND;
  const float* r1a = e2p + (size_t)sl1 * ND;
  const float* r1b = r1a + (size_t)MAXSLOT * ND;
  const float* hr = hf + (size_t)row * ND;
  float v[3]; float s = 0.f, sq = 0.f;
  #pragma unroll
  for (int i = 0; i < 3; i++){
    int idx = t + i * 256;
    float c = w0 * (r0a[idx] + r0b[idx]) + w1 * (r1a[idx] + r1b[idx]);
    float xv = hr[idx] + c;
    v[i] = xv; s += xv; sq += xv * xv;
  }
  __shared__ float rs[4], rq[4];
  #pragma unroll
  for (int d = 32; d >= 1; d >>= 1){ s += __shfl_xor(s, d); sq += __shfl_xor(sq, d); }
  int w = t >> 6;
  if ((t & 63) == 0){ rs[w] = s; rq[w] = sq; }
  __syncthreads();
  s = rs[0] + rs[1] + rs[2] + rs[3];
  sq = rq[0] + rq[1] + rq[2] + rq[3];
  float mean = s * (1.f / ND);
  float var = sq * (1.f / ND) - mean * mean;
  float rstd = rsqrtf(var + 1e-5f);
  #pragma unroll
  for (int i = 0; i < 3; i++){
    int idx = t + i * 256;
    float y = (v[i] - mean) * rstd * g[idx] + bb[idx];
    out[(size_t)row * ND + idx] = attn_x[(size_t)row * ND + idx] + y;
  }
}

// ================= host =================
extern "C" void kernel_launch(void* const* d_in, const int* in_sizes, int n_in,
                              void* d_out, int out_size, void* d_ws, size_t ws_size,
                              hipStream_t stream){
  const float* x        = (const float*)d_in[0];
  const float* ln_att_g = (const float*)d_in[2];
  const float* ln_att_b = (const float*)d_in[3];
  const float* wq = (const float*)d_in[4];  const float* bq = (const float*)d_in[5];
  const float* wk = (const float*)d_in[6];  const float* bk = (const float*)d_in[7];
  const float* wv = (const float*)d_in[8];  const float* bv = (const float*)d_in[9];
  const float* wo = (const float*)d_in[10]; const float* bo = (const float*)d_in[11];
  const float* ln_ff_g = (const float*)d_in[12];
  const float* ln_ff_b = (const float*)d_in[13];
  const float* gate_w  = (const float*)d_in[14];
  const float* gate_b  = (const float*)d_in[15];
  const float* w1 = (const float*)d_in[16]; const float* b1 = (const float*)d_in[17];
  const float* w2 = (const float*)d_in[18]; const float* b2 = (const float*)d_in[19];
  const float* moe_g = (const float*)d_in[20];
  const float* moe_b = (const float*)d_in[21];

  uint8_t* p = (uint8_t*)d_ws;
  auto alloc = [&](size_t bytes) -> void* {
    void* r = (void*)p;
    p += (bytes + 255) & ~(size_t)255;
    return r;
  };
  // wqkv_t (2304x768) and wo_t (768x768) contiguous: one transpose4 dispatch
  bf16* wqkv_t  = (bf16*)alloc((size_t)(2304 + 768) * 768 * 2);
  bf16* wo_t    = wqkv_t + (size_t)2304 * 768;
  bf16* w1_t    = (bf16*)alloc((size_t)NE * NHID * ND * 2);
  bf16* w2_t    = (bf16*)alloc((size_t)NE * ND * NHID * 2);
  float* bias_qkv = (float*)alloc(2304 * 4);
  bf16* a_bf    = (bf16*)alloc((size_t)NTOK * ND * 2);
  bf16* qkv     = (bf16*)alloc((size_t)NTOK * 2304 * 2);
  bf16* vT      = (bf16*)alloc((size_t)NB * NH * 64 * NS * 2);
  bf16* ctx     = (bf16*)alloc((size_t)NTOK * ND * 2);
  float* attn_x = (float*)alloc((size_t)NTOK * ND * 4);
  float* h_f    = (float*)alloc((size_t)NTOK * ND * 4);
  bf16* h_b     = (bf16*)alloc((size_t)NTOK * ND * 2);
  int*  ridx    = (int*)alloc(NASSIGN * 4);
  float* rwt    = (float*)alloc(NASSIGN * 4);
  int* counts   = (int*)alloc(NE * 4);
  int* poff     = (int*)alloc(NE * 4);
  int* cursor   = (int*)alloc(NE * 4);
  int* chunk_e  = (int*)alloc(MAXCH * 4);
  int* tok_list = (int*)alloc(MAXSLOT * 4);
  int* slot_of  = (int*)alloc(NASSIGN * 4);
  bf16* e1      = (bf16*)alloc((size_t)MAXSLOT * NHID * 2);
  float* e2p    = (float*)alloc((size_t)2 * MAXSLOT * ND * 4);  // split-K fp32 partials

  hipMemsetAsync(counts, 0, NE * 4, stream);
  hipMemsetAsync(cursor, 0, NE * 4, stream);

  // weight prep: one batched dispatch for wq/wk/wv/wo, one each for w1/w2
  Ptr4 s4; s4.p0 = wq; s4.p1 = wk; s4.p2 = wv; s4.p3 = wo;
  transpose4_kernel<<<dim3(12, 12, 4), 256, 0, stream>>>(s4, wqkv_t);
  transpose_convert_kernel<<<dim3(48, 12, NE), 256, 0, stream>>>(w1, w1_t, 768, 3072);
  transpose_convert_kernel<<<dim3(12, 48, NE), 256, 0, stream>>>(w2, w2_t, 3072, 768);
  concat3_kernel<<<dim3(9), 256, 0, stream>>>(bq, bk, bv, bias_qkv);

  // attention path
  ln_kernel<false, true><<<dim3(NTOK), 256, 0, stream>>>(x, ln_att_g, ln_att_b, nullptr, a_bf);
  gemm_kernel<1, false, false, true, false, false, false><<<dim3(18, 32), 256, 0, stream>>>(
      a_bf, ND, wqkv_t, bias_qkv, qkv, 2304, nullptr, 2304, ND, ND, 0, nullptr, nullptr);
  vtrans_kernel<<<dim3(16, 1, NB * NH), 256, 0, stream>>>(qkv, vT);
  flash_attn_kernel<<<dim3(768), 256, 0, stream>>>(qkv, vT, ctx);
  gemm_kernel<1, false, false, false, true, false, false><<<dim3(6, 32), 256, 0, stream>>>(
      ctx, ND, wo_t, bo, attn_x, ND, x, ND, ND, ND, 0, nullptr, nullptr);

  // MoE path
  ln_kernel<true, true><<<dim3(NTOK), 256, 0, stream>>>(attn_x, ln_ff_g, ln_ff_b, h_f, h_b);
  gate_kernel<<<dim3(NTOK / 32), 256, 0, stream>>>(h_f, gate_w, gate_b, ridx, rwt, counts);
  scan_kernel<<<dim3(1), 256, 0, stream>>>(counts, poff, chunk_e, tok_list);
  scatter_kernel<<<dim3(NASSIGN / 256), 256, 0, stream>>>(ridx, poff, cursor, tok_list, slot_of);
  // e1: wide 128x256 blocks, 8 waves; grid 12 n-tiles x 72 chunks = 864 blocks
  gemm_wide_kernel<true, true, true, true><<<dim3(12, 72), 512, 0, stream>>>(
      h_b, ND, w1_t, b1, e1, NHID, NHID, ND, chunk_e, tok_list);
  // e2: split-K=2 (K=1536 each), flat 864-block grid with XCD-grouped decode,
  // fp32 partials to e2p[0] / e2p[1]
  gemm_kernel<1, false, false, false, false, true, true><<<dim3(864), 256, 0, stream>>>(
      e1, NHID, w2_t, b2, e2p, ND, nullptr, ND, NHID / 2, NHID,
      (size_t)MAXSLOT * ND, chunk_e, nullptr);
  combine_kernel<<<dim3(NTOK), 256, 0, stream>>>(e2p, slot_of, rwt, h_f, attn_x, moe_g, moe_b,
                                                 (float*)d_out);
}

// Round 8
// 537.600 us; speedup vs baseline: 1.4058x; 1.4058x over previous
//
#include <hip/hip_runtime.h>
#include <hip/hip_bf16.h>
#include <stdint.h>

using bf16 = __hip_bfloat16;
typedef short s16x8 __attribute__((ext_vector_type(8)));
typedef float f32x4 __attribute__((ext_vector_type(4)));

#define NB 4
#define NS 1024
#define ND 768
#define NH 12
#define NE 8
#define NHID 3072
#define NTOK 4096
#define NASSIGN 8192
#define MAXCH 72               // sum ceil(counts[e]/128) <= 64 + 8
#define MAXSLOT (MAXCH * 128)  // 9216

__device__ __forceinline__ float bf2f(bf16 v){ return __bfloat162float(v); }
__device__ __forceinline__ bf16 f2bf(float v){ return __float2bfloat16(v); }

__device__ __forceinline__ void gload_lds16(const bf16* g, bf16* l){
  __builtin_amdgcn_global_load_lds((const __attribute__((address_space(1))) void*)g,
                                   (__attribute__((address_space(3))) void*)l, 16, 0, 0);
}

// ---------------- transpose + fp32->bf16 convert, 64x64 tile, 16B loads/stores
__device__ __forceinline__ void transpose64_body(const float* __restrict__ src,
                                                 bf16* __restrict__ dst,
                                                 int K, int N, int n0, int k0, int t){
  __shared__ float tile[64][65];
  int kr = t >> 4, c4 = (t & 15) * 4;
  #pragma unroll
  for (int i = 0; i < 4; i++){
    int k = kr + i * 16;
    float4 v = *(const float4*)(src + (size_t)(k0 + k) * N + n0 + c4);
    tile[k][c4]     = v.x;
    tile[k][c4 + 1] = v.y;
    tile[k][c4 + 2] = v.z;
    tile[k][c4 + 3] = v.w;
  }
  __syncthreads();
  int nr = t >> 3, k8 = (t & 7) * 8;
  #pragma unroll
  for (int i = 0; i < 2; i++){
    int n = nr + i * 32;
    short vv[8];
    #pragma unroll
    for (int j = 0; j < 8; j++){
      bf16 x = f2bf(tile[k8 + j][n]);
      vv[j] = *(short*)&x;
    }
    *(s16x8*)(dst + (size_t)(n0 + n) * K + k0 + k8) = *(s16x8*)vv;
  }
}

__global__ void transpose_convert_kernel(const float* __restrict__ src, bf16* __restrict__ dst,
                                         int K, int N){
  int bz = blockIdx.z;
  transpose64_body(src + (size_t)bz * K * N, dst + (size_t)bz * N * K,
                   K, N, blockIdx.x * 64, blockIdx.y * 64, threadIdx.x);
}

// four 768x768 fp32->bf16 transposes in one dispatch (wq,wk,wv,wo -> contiguous dst)
struct Ptr4 { const float* p0; const float* p1; const float* p2; const float* p3; };
__global__ void transpose4_kernel(Ptr4 s4, bf16* __restrict__ dst){
  int z = blockIdx.z;
  const float* src = (z == 0) ? s4.p0 : (z == 1) ? s4.p1 : (z == 2) ? s4.p2 : s4.p3;
  transpose64_body(src, dst + (size_t)z * 768 * 768,
                   768, 768, blockIdx.x * 64, blockIdx.y * 64, threadIdx.x);
}

// ---------------- concat 3 bias vectors [768] -> [2304]
__global__ void concat3_kernel(const float* __restrict__ a, const float* __restrict__ b,
                               const float* __restrict__ c, float* __restrict__ out){
  int i = blockIdx.x * 256 + threadIdx.x;
  if (i >= 3 * ND) return;
  float v = (i < ND) ? a[i] : (i < 2 * ND ? b[i - ND] : c[i - 2 * ND]);
  out[i] = v;
}

// ---------------- LayerNorm row kernel (768 per row, 256 threads)
template<bool OF, bool OB>
__global__ void ln_kernel(const float* __restrict__ in, const float* __restrict__ g,
                          const float* __restrict__ bb, float* __restrict__ of,
                          bf16* __restrict__ ob){
  int row = blockIdx.x, t = threadIdx.x;
  const float* x = in + (size_t)row * ND;
  float v[3]; float s = 0.f, sq = 0.f;
  #pragma unroll
  for (int i = 0; i < 3; i++){ v[i] = x[t + i * 256]; s += v[i]; sq += v[i] * v[i]; }
  __shared__ float rs[4], rq[4];
  #pragma unroll
  for (int d = 32; d >= 1; d >>= 1){ s += __shfl_xor(s, d); sq += __shfl_xor(sq, d); }
  int w = t >> 6;
  if ((t & 63) == 0){ rs[w] = s; rq[w] = sq; }
  __syncthreads();
  s = rs[0] + rs[1] + rs[2] + rs[3];
  sq = rq[0] + rq[1] + rq[2] + rq[3];
  float mean = s * (1.f / ND);
  float var = sq * (1.f / ND) - mean * mean;
  float rstd = rsqrtf(var + 1e-5f);
  #pragma unroll
  for (int i = 0; i < 3; i++){
    int idx = t + i * 256;
    float y = (v[i] - mean) * rstd * g[idx] + bb[idx];
    if (OF) of[(size_t)row * ND + idx] = y;
    if (OB) ob[(size_t)row * ND + idx] = f2bf(y);
  }
}

// ---------------- GEMM: C[chunk rows][N] = A @ Bt^T + bias
// SPLITZ: e2 decode — 6 n-tiles of one (chunk,ks) group land on one XCD.
// XMAJ: e1 decode — chunk-major per XCD: xcd = bid&7 owns chunks [9*xcd, 9*xcd+9),
//   all 24 n-tiles. Each chunk's A panel is fetched into exactly ONE XCD L2
//   (grid 1728 = 8 * 9 * 24, bijective).
template<int GROUP, bool GATHER, bool RELU, bool OBF, bool RESID, bool SEG, bool SPLITZ, bool XMAJ>
__global__ __launch_bounds__(256, 4)
void gemm_kernel(const bf16* __restrict__ A, int ldA,
                 const bf16* __restrict__ BtB,
                 const float* __restrict__ biasB,
                 void* __restrict__ Cv, int ldC,
                 const float* __restrict__ resid,
                 int N, int K, int ldB, size_t czstride,
                 const int* __restrict__ chunk_e, const int* __restrict__ tok){
  __shared__ __align__(16) bf16 sA[2][128 * 32];
  __shared__ __align__(16) bf16 sB[2][128 * 32];

  int t = threadIdx.x;
  int lane = t & 63, wv = t >> 6;
  int c0i = wv * 128 + lane;          // staging chunk id (and c0i+64)
  int r0  = c0i >> 2;                 // tile-local row of chunk0; chunk1 row = r0+16
  int kk  = (c0i & 3) * 8;
  int nt, cbase = 0, ks = 0;
  if (SPLITZ){
    int l = blockIdx.x, xcd = l & 7, slot = l >> 3;
    int grp = xcd + 8 * (slot / 6);   // 144 (chunk,ks) groups, 18 per XCD
    nt = slot % 6;
    cbase = grp % MAXCH;
    ks = grp / MAXCH;
  } else if (XMAJ){
    int l = blockIdx.x, xcd = l & 7, slot = l >> 3;   // slot 0..215
    cbase = xcd * 9 + slot / 24;      // 9 chunks per XCD
    nt = slot % 24;
  } else {
    nt = blockIdx.x;
  }
  int koff = ks * K;
  float* Cfs = (float*)Cv + (size_t)ks * czstride;
  int wm = (wv >> 1) * 64, wn = (wv & 1) * 64;
  int l16 = lane & 15, q4 = lane >> 4;
  int aoff[4], boff[4];
  #pragma unroll
  for (int mi = 0; mi < 4; mi++) aoff[mi] = (wm + mi * 16 + l16) * 32 + q4 * 8;
  #pragma unroll
  for (int ni = 0; ni < 4; ni++) boff[ni] = (wn + ni * 16 + l16) * 32 + q4 * 8;

  for (int g = 0; g < GROUP; g++){
    int c = (SPLITZ || XMAJ) ? cbase : blockIdx.y * GROUP + g;
    int e = 0;
    if (SEG){ e = chunk_e[c]; if (e < 0) break; }
    const bf16* Bt = SEG ? BtB + (size_t)e * N * ldB : BtB;
    const float* bias = SEG ? biasB + (size_t)e * N : biasB;
    size_t arow0, arow1;
    int m0 = c * 128 + r0, m1 = m0 + 16;
    if (GATHER){ arow0 = (size_t)tok[m0]; arow1 = (size_t)tok[m1]; }
    else       { arow0 = (size_t)m0;      arow1 = (size_t)m1; }
    const bf16* gA0 = A + arow0 * ldA + koff + kk;
    const bf16* gA1 = A + arow1 * ldA + koff + kk;
    const bf16* gB0 = Bt + (size_t)(nt * 128 + r0) * ldB + koff + kk;
    const bf16* gB1 = Bt + (size_t)(nt * 128 + r0 + 16) * ldB + koff + kk;

    if (g > 0) __syncthreads();  // protect LDS reuse across chunks

    f32x4 acc[4][4] = {};
    gload_lds16(gA0, &sA[0][(size_t)c0i * 8]);
    gload_lds16(gA1, &sA[0][(size_t)(c0i + 64) * 8]);
    gload_lds16(gB0, &sB[0][(size_t)c0i * 8]);
    gload_lds16(gB1, &sB[0][(size_t)(c0i + 64) * 8]);

    int nk = K >> 5;
    for (int ki = 0; ki < nk; ki++){
      int cur = ki & 1;
      __syncthreads();
      if (ki + 1 < nk){
        int nxt = cur ^ 1, off = (ki + 1) * 32;
        gload_lds16(gA0 + off, &sA[nxt][(size_t)c0i * 8]);
        gload_lds16(gA1 + off, &sA[nxt][(size_t)(c0i + 64) * 8]);
        gload_lds16(gB0 + off, &sB[nxt][(size_t)c0i * 8]);
        gload_lds16(gB1 + off, &sB[nxt][(size_t)(c0i + 64) * 8]);
      }
      s16x8 af[4], bfr[4];
      #pragma unroll
      for (int mi = 0; mi < 4; mi++) af[mi] = *(const s16x8*)(&sA[cur][0] + aoff[mi]);
      #pragma unroll
      for (int ni = 0; ni < 4; ni++) bfr[ni] = *(const s16x8*)(&sB[cur][0] + boff[ni]);
      #pragma unroll
      for (int mi = 0; mi < 4; mi++)
        #pragma unroll
        for (int ni = 0; ni < 4; ni++)
          acc[mi][ni] = __builtin_amdgcn_mfma_f32_16x16x32_bf16(af[mi], bfr[ni], acc[mi][ni], 0, 0, 0);
    }

    #pragma unroll
    for (int mi = 0; mi < 4; mi++){
      #pragma unroll
      for (int ni = 0; ni < 4; ni++){
        int col = nt * 128 + wn + ni * 16 + l16;
        float bv = (!SPLITZ || ks == 0) ? bias[col] : 0.f;
        #pragma unroll
        for (int r = 0; r < 4; r++){
          size_t crow = (size_t)(c * 128 + wm + mi * 16 + q4 * 4 + r);
          float v = acc[mi][ni][r] + bv;
          if (RELU) v = fmaxf(v, 0.f);
          if (RESID) v += resid[crow * ldC + col];
          if (OBF) ((bf16*)Cv)[crow * ldC + col] = f2bf(v);
          else     Cfs[crow * ldC + col] = v;
        }
      }
    }
  }
}

// ---------------- V transpose: qkv v-cols [b,s,h,d] -> vT [b,h,d,s] (bf16)
__global__ void vtrans_kernel(const bf16* __restrict__ qkv, bf16* __restrict__ vT){
  __shared__ bf16 tile[64][65];
  int bh = blockIdx.z; int b = bh / NH, h = bh % NH;
  int s0 = blockIdx.x * 64;
  int t = threadIdx.x;
  int sr = t >> 3, d8 = (t & 7) * 8;
  #pragma unroll
  for (int i = 0; i < 2; i++){
    int s = sr + i * 32;
    s16x8 v = *(const s16x8*)(qkv + (size_t)(b * NS + s0 + s) * 2304 + 1536 + h * 64 + d8);
    #pragma unroll
    for (int j = 0; j < 8; j++) tile[d8 + j][s] = ((bf16*)&v)[j];
  }
  __syncthreads();
  int dr = t >> 3, s8 = (t & 7) * 8;
  #pragma unroll
  for (int i = 0; i < 2; i++){
    int d = dr + i * 32;
    short vv[8];
    #pragma unroll
    for (int j = 0; j < 8; j++){ bf16 x = tile[d][s8 + j]; vv[j] = *(short*)&x; }
    *(s16x8*)(vT + ((size_t)bh * 64 + d) * NS + s0 + s8) = *(s16x8*)vv;
  }
}

// ---------------- flash attention v3 (unchanged)
#define SPAD 72
__global__ __launch_bounds__(256, 3)
void flash_attn_kernel(const bf16* __restrict__ qkv, const bf16* __restrict__ vT,
                       bf16* __restrict__ ctx){
  __shared__ __align__(16) bf16 sK[2][64 * 64];
  __shared__ __align__(16) bf16 sV[2][64 * 64];
  __shared__ __align__(16) bf16 sP[4][16 * SPAD];
  int id = blockIdx.x;
  int bh = id % 48;
  int qt = 15 - (id / 48);
  int b = bh / NH, h = bh % NH;
  int t = threadIdx.x, lane = t & 63, wv = t >> 6;
  int l16 = lane & 15, q4 = lane >> 4;
  int q0 = qt * 64 + wv * 16;
  const size_t ldq = 2304;
  const bf16* qbase = qkv + (size_t)(b * NS) * ldq + h * 64;
  const bf16* kbase = qbase + 768;
  const bf16* vtb = vT + (size_t)bh * 64 * NS;
  bf16* sPw = &sP[wv][0];
  const f32x4 fzero = {0.f, 0.f, 0.f, 0.f};

  s16x8 qf[2];
  #pragma unroll
  for (int kh = 0; kh < 2; kh++)
    qf[kh] = *(const s16x8*)(qbase + (size_t)(q0 + l16) * ldq + kh * 32 + q4 * 8);

  f32x4 O[4] = {};
  float ms[4], ls[4];
  #pragma unroll
  for (int r = 0; r < 4; r++){ ms[r] = -1e30f; ls[r] = 0.f; }

  int sub = lane >> 3, rawc = lane & 7;
  auto stage = [&](int buf, int key0){
    #pragma unroll
    for (int i = 0; i < 2; i++){
      int rk = wv * 8 + sub + i * 32;          // key row (K) / dh row (V)
      int cs = (rawc ^ (rk & 7)) * 8;          // swizzled source col (elems)
      gload_lds16(kbase + (size_t)(key0 + rk) * ldq + cs, &sK[buf][wv * 512 + i * 2048]);
      gload_lds16(vtb + (size_t)rk * NS + key0 + cs,      &sV[buf][wv * 512 + i * 2048]);
    }
  };

  int ntiles = qt + 1;
  stage(0, 0);
  for (int ti = 0; ti < ntiles; ti++){
    int cur = ti & 1, key0 = ti * 64;
    __syncthreads();                       // drains own staging loads + barrier
    if (ti + 1 < ntiles) stage(cur ^ 1, (ti + 1) * 64);
    if (key0 <= q0 + 15){
      const bf16* sKc = &sK[cur][0];
      const bf16* sVc = &sV[cur][0];
      s16x8 kf[4][2], vf[4][2];
      #pragma unroll
      for (int ni = 0; ni < 4; ni++){
        int krow = ni * 16 + l16;
        #pragma unroll
        for (int kh = 0; kh < 2; kh++)
          kf[ni][kh] = *(const s16x8*)(sKc + krow * 64 + (((kh * 4 + q4) ^ (krow & 7)) * 8));
      }
      #pragma unroll
      for (int dt = 0; dt < 4; dt++){
        int vrow = dt * 16 + l16;
        #pragma unroll
        for (int kh = 0; kh < 2; kh++)
          vf[dt][kh] = *(const s16x8*)(sVc + vrow * 64 + (((kh * 4 + q4) ^ (vrow & 7)) * 8));
      }
      f32x4 Sf[4];
      #pragma unroll
      for (int ni = 0; ni < 4; ni++){
        Sf[ni] = __builtin_amdgcn_mfma_f32_16x16x32_bf16(qf[0], kf[ni][0], fzero, 0, 0, 0);
        Sf[ni] = __builtin_amdgcn_mfma_f32_16x16x32_bf16(qf[1], kf[ni][1], Sf[ni], 0, 0, 0);
      }
      bool need_mask = (key0 + 63 >= q0);  // wave-uniform
      #pragma unroll
      for (int r = 0; r < 4; r++){
        int qrow = q0 + q4 * 4 + r;
        float sv[4];
        #pragma unroll
        for (int ni = 0; ni < 4; ni++){
          sv[ni] = Sf[ni][r] * 0.125f;
          if (need_mask && (key0 + ni * 16 + l16 > qrow)) sv[ni] = -1e30f;
        }
        float mx = fmaxf(fmaxf(sv[0], sv[1]), fmaxf(sv[2], sv[3]));
        #pragma unroll
        for (int d = 8; d >= 1; d >>= 1) mx = fmaxf(mx, __shfl_xor(mx, d));
        float mnew = fmaxf(ms[r], mx);
        float alpha = __expf(ms[r] - mnew);
        float p[4], psum = 0.f;
        #pragma unroll
        for (int ni = 0; ni < 4; ni++){ p[ni] = __expf(sv[ni] - mnew); psum += p[ni]; }
        #pragma unroll
        for (int d = 8; d >= 1; d >>= 1) psum += __shfl_xor(psum, d);
        ls[r] = ls[r] * alpha + psum;
        ms[r] = mnew;
        #pragma unroll
        for (int dt = 0; dt < 4; dt++) O[dt][r] *= alpha;
        int prow = q4 * 4 + r;
        #pragma unroll
        for (int ni = 0; ni < 4; ni++)
          sPw[prow * SPAD + ni * 16 + l16] = f2bf(p[ni]);
      }
      s16x8 pf[2];
      #pragma unroll
      for (int kh = 0; kh < 2; kh++)
        pf[kh] = *(const s16x8*)(sPw + l16 * SPAD + kh * 32 + q4 * 8);
      #pragma unroll
      for (int dt = 0; dt < 4; dt++){
        O[dt] = __builtin_amdgcn_mfma_f32_16x16x32_bf16(pf[0], vf[dt][0], O[dt], 0, 0, 0);
        O[dt] = __builtin_amdgcn_mfma_f32_16x16x32_bf16(pf[1], vf[dt][1], O[dt], 0, 0, 0);
      }
    }
  }

  #pragma unroll
  for (int r = 0; r < 4; r++){
    float inv = 1.f / ls[r];
    int qrow = q0 + q4 * 4 + r;
    #pragma unroll
    for (int dt = 0; dt < 4; dt++)
      ctx[(size_t)(b * NS + qrow) * ND + h * 64 + dt * 16 + l16] = f2bf(O[dt][r] * inv);
  }
}

// ---------------- gate v2: 128 blocks x 32 tokens; LDS count aggregation
__global__ __launch_bounds__(256)
void gate_kernel(const float* __restrict__ h, const float* __restrict__ gw,
                 const float* __restrict__ gb, int* __restrict__ ridx,
                 float* __restrict__ rw, int* __restrict__ counts){
  __shared__ float sgw[NE * ND];   // transposed: sgw[e*ND+i] -> stride-1 reads
  __shared__ int scnt[NE];
  int t = threadIdx.x;
  if (t < NE) scnt[t] = 0;
  for (int idx = t; idx < ND * NE; idx += 256){
    int i = idx >> 3, e = idx & 7;
    sgw[e * ND + i] = gw[idx];
  }
  __syncthreads();
  int lane = t & 63, wv = t >> 6;
  for (int it = 0; it < 8; it++){
    int tok = blockIdx.x * 32 + it * 4 + wv;
    const float* hr = h + (size_t)tok * ND;
    float acc[NE] = {};
    #pragma unroll
    for (int ii = 0; ii < 12; ii++){
      int i = lane + ii * 64;
      float hv = hr[i];
      #pragma unroll
      for (int e = 0; e < NE; e++) acc[e] += hv * sgw[e * ND + i];
    }
    #pragma unroll
    for (int e = 0; e < NE; e++)
      #pragma unroll
      for (int d = 32; d >= 1; d >>= 1) acc[e] += __shfl_xor(acc[e], d);
    if (lane == 0){
      float v0 = -1e30f, v1 = -1e30f; int i0 = 0, i1 = 0;
      #pragma unroll
      for (int e = 0; e < NE; e++){
        float v = acc[e] + gb[e];
        if (v > v0){ v1 = v0; i1 = i0; v0 = v; i0 = e; }
        else if (v > v1){ v1 = v; i1 = e; }
      }
      float w0 = 1.f / (1.f + __expf(v1 - v0));
      ridx[tok * 2] = i0; ridx[tok * 2 + 1] = i1;
      rw[tok * 2] = w0;  rw[tok * 2 + 1] = 1.f - w0;
      atomicAdd(&scnt[i0], 1);
      atomicAdd(&scnt[i1], 1);
    }
  }
  __syncthreads();
  if (t < NE) atomicAdd(&counts[t], scnt[t]);
}

// scan: padded (128-aligned) expert offsets + chunk->expert map + tok_list prefill
__global__ void scan_kernel(const int* __restrict__ counts, int* __restrict__ poff,
                            int* __restrict__ chunk_e, int* __restrict__ tok_list){
  int t = threadIdx.x;
  for (int i = t; i < MAXSLOT; i += 256) tok_list[i] = 0;
  if (t == 0){
    int s = 0, c = 0;
    for (int e = 0; e < NE; e++){
      poff[e] = s;
      int nch = (counts[e] + 127) >> 7;
      for (int i = 0; i < nch; i++) chunk_e[c++] = e;
      s += nch << 7;
    }
    for (; c < MAXCH; c++) chunk_e[c] = -1;
  }
}

// scatter v2: wave-aggregated atomics (1 atomic per expert per wave)
__global__ void scatter_kernel(const int* __restrict__ ridx, const int* __restrict__ poff,
                               int* __restrict__ cursor, int* __restrict__ tok_list,
                               int* __restrict__ slot_of){
  int tk = blockIdx.x * 256 + threadIdx.x;
  int lane = threadIdx.x & 63;
  int e = ridx[tk];
  unsigned long long lmask = (1ull << lane) - 1;  // bits below lane
  int slot = 0;
  #pragma unroll
  for (int ee = 0; ee < NE; ee++){
    unsigned long long mask = __ballot(e == ee);
    if (mask == 0ull) continue;
    int leader = __ffsll((unsigned long long)mask) - 1;
    int base = 0;
    if (lane == leader) base = atomicAdd(&cursor[ee], __popcll(mask));
    base = __shfl(base, leader);
    if (e == ee) slot = poff[ee] + base + __popcll(mask & lmask);
  }
  tok_list[slot] = tk >> 1;
  slot_of[tk] = slot;
}

// ---------------- combine: core = w0*(p0[s0]+p1[s0]) + w1*(p0[s1]+p1[s1]);
// out = attn_x + LN(h+core).  e2 partials are fp32 (split-K halves).
__global__ void combine_kernel(const float* __restrict__ e2p, const int* __restrict__ slot_of,
                               const float* __restrict__ rw, const float* __restrict__ hf,
                               const float* __restrict__ attn_x, const float* __restrict__ g,
                               const float* __restrict__ bb, float* __restrict__ out){
  int row = blockIdx.x, t = threadIdx.x;
  int sl0 = slot_of[row * 2], sl1 = slot_of[row * 2 + 1];
  float w0 = rw[row * 2], w1 = rw[row * 2 + 1];
  const float* r0a = e2p + (size_t)sl0 * ND;
  const float* r0b = r0a + (size_t)MAXSLOT * ND;
  const float* r1a = e2p + (size_t)sl1 * ND;
  const float* r1b = r1a + (size_t)MAXSLOT * ND;
  const float* hr = hf + (size_t)row * ND;
  float v[3]; float s = 0.f, sq = 0.f;
  #pragma unroll
  for (int i = 0; i < 3; i++){
    int idx = t + i * 256;
    float c = w0 * (r0a[idx] + r0b[idx]) + w1 * (r1a[idx] + r1b[idx]);
    float xv = hr[idx] + c;
    v[i] = xv; s += xv; sq += xv * xv;
  }
  __shared__ float rs[4], rq[4];
  #pragma unroll
  for (int d = 32; d >= 1; d >>= 1){ s += __shfl_xor(s, d); sq += __shfl_xor(sq, d); }
  int w = t >> 6;
  if ((t & 63) == 0){ rs[w] = s; rq[w] = sq; }
  __syncthreads();
  s = rs[0] + rs[1] + rs[2] + rs[3];
  sq = rq[0] + rq[1] + rq[2] + rq[3];
  float mean = s * (1.f / ND);
  float var = sq * (1.f / ND) - mean * mean;
  float rstd = rsqrtf(var + 1e-5f);
  #pragma unroll
  for (int i = 0; i < 3; i++){
    int idx = t + i * 256;
    float y = (v[i] - mean) * rstd * g[idx] + bb[idx];
    out[(size_t)row * ND + idx] = attn_x[(size_t)row * ND + idx] + y;
  }
}

// ================= host =================
extern "C" void kernel_launch(void* const* d_in, const int* in_sizes, int n_in,
                              void* d_out, int out_size, void* d_ws, size_t ws_size,
                              hipStream_t stream){
  const float* x        = (const float*)d_in[0];
  const float* ln_att_g = (const float*)d_in[2];
  const float* ln_att_b = (const float*)d_in[3];
  const float* wq = (const float*)d_in[4];  const float* bq = (const float*)d_in[5];
  const float* wk = (const float*)d_in[6];  const float* bk = (const float*)d_in[7];
  const float* wv = (const float*)d_in[8];  const float* bv = (const float*)d_in[9];
  const float* wo = (const float*)d_in[10]; const float* bo = (const float*)d_in[11];
  const float* ln_ff_g = (const float*)d_in[12];
  const float* ln_ff_b = (const float*)d_in[13];
  const float* gate_w  = (const float*)d_in[14];
  const float* gate_b  = (const float*)d_in[15];
  const float* w1 = (const float*)d_in[16]; const float* b1 = (const float*)d_in[17];
  const float* w2 = (const float*)d_in[18]; const float* b2 = (const float*)d_in[19];
  const float* moe_g = (const float*)d_in[20];
  const float* moe_b = (const float*)d_in[21];

  uint8_t* p = (uint8_t*)d_ws;
  auto alloc = [&](size_t bytes) -> void* {
    void* r = (void*)p;
    p += (bytes + 255) & ~(size_t)255;
    return r;
  };
  // wqkv_t (2304x768) and wo_t (768x768) contiguous: one transpose4 dispatch
  bf16* wqkv_t  = (bf16*)alloc((size_t)(2304 + 768) * 768 * 2);
  bf16* wo_t    = wqkv_t + (size_t)2304 * 768;
  bf16* w1_t    = (bf16*)alloc((size_t)NE * NHID * ND * 2);
  bf16* w2_t    = (bf16*)alloc((size_t)NE * ND * NHID * 2);
  float* bias_qkv = (float*)alloc(2304 * 4);
  bf16* a_bf    = (bf16*)alloc((size_t)NTOK * ND * 2);
  bf16* qkv     = (bf16*)alloc((size_t)NTOK * 2304 * 2);
  bf16* vT      = (bf16*)alloc((size_t)NB * NH * 64 * NS * 2);
  bf16* ctx     = (bf16*)alloc((size_t)NTOK * ND * 2);
  float* attn_x = (float*)alloc((size_t)NTOK * ND * 4);
  float* h_f    = (float*)alloc((size_t)NTOK * ND * 4);
  bf16* h_b     = (bf16*)alloc((size_t)NTOK * ND * 2);
  int*  ridx    = (int*)alloc(NASSIGN * 4);
  float* rwt    = (float*)alloc(NASSIGN * 4);
  int* counts   = (int*)alloc(NE * 4);
  int* poff     = (int*)alloc(NE * 4);
  int* cursor   = (int*)alloc(NE * 4);
  int* chunk_e  = (int*)alloc(MAXCH * 4);
  int* tok_list = (int*)alloc(MAXSLOT * 4);
  int* slot_of  = (int*)alloc(NASSIGN * 4);
  bf16* e1      = (bf16*)alloc((size_t)MAXSLOT * NHID * 2);
  float* e2p    = (float*)alloc((size_t)2 * MAXSLOT * ND * 4);  // split-K fp32 partials

  hipMemsetAsync(counts, 0, NE * 4, stream);
  hipMemsetAsync(cursor, 0, NE * 4, stream);

  // weight prep: one batched dispatch for wq/wk/wv/wo, one each for w1/w2
  Ptr4 s4; s4.p0 = wq; s4.p1 = wk; s4.p2 = wv; s4.p3 = wo;
  transpose4_kernel<<<dim3(12, 12, 4), 256, 0, stream>>>(s4, wqkv_t);
  transpose_convert_kernel<<<dim3(48, 12, NE), 256, 0, stream>>>(w1, w1_t, 768, 3072);
  transpose_convert_kernel<<<dim3(12, 48, NE), 256, 0, stream>>>(w2, w2_t, 3072, 768);
  concat3_kernel<<<dim3(9), 256, 0, stream>>>(bq, bk, bv, bias_qkv);

  // attention path
  ln_kernel<false, true><<<dim3(NTOK), 256, 0, stream>>>(x, ln_att_g, ln_att_b, nullptr, a_bf);
  gemm_kernel<1, false, false, true, false, false, false, false><<<dim3(18, 32), 256, 0, stream>>>(
      a_bf, ND, wqkv_t, bias_qkv, qkv, 2304, nullptr, 2304, ND, ND, 0, nullptr, nullptr);
  vtrans_kernel<<<dim3(16, 1, NB * NH), 256, 0, stream>>>(qkv, vT);
  flash_attn_kernel<<<dim3(768), 256, 0, stream>>>(qkv, vT, ctx);
  gemm_kernel<1, false, false, false, true, false, false, false><<<dim3(6, 32), 256, 0, stream>>>(
      ctx, ND, wo_t, bo, attn_x, ND, x, ND, ND, ND, 0, nullptr, nullptr);

  // MoE path
  ln_kernel<true, true><<<dim3(NTOK), 256, 0, stream>>>(attn_x, ln_ff_g, ln_ff_b, h_f, h_b);
  gate_kernel<<<dim3(NTOK / 32), 256, 0, stream>>>(h_f, gate_w, gate_b, ridx, rwt, counts);
  scan_kernel<<<dim3(1), 256, 0, stream>>>(counts, poff, chunk_e, tok_list);
  scatter_kernel<<<dim3(NASSIGN / 256), 256, 0, stream>>>(ridx, poff, cursor, tok_list, slot_of);
  // e1: flat 1728-block grid, XCD chunk-major decode (XMAJ) — each chunk's
  // A panel lives in exactly one XCD L2
  gemm_kernel<1, true, true, true, false, true, false, true><<<dim3(1728), 256, 0, stream>>>(
      h_b, ND, w1_t, b1, e1, NHID, nullptr, NHID, ND, ND, 0, chunk_e, tok_list);
  // e2: split-K=2 (K=1536 each), flat 864-block grid with XCD-grouped decode,
  // fp32 partials to e2p[0] / e2p[1]
  gemm_kernel<1, false, false, false, false, true, true, false><<<dim3(864), 256, 0, stream>>>(
      e1, NHID, w2_t, b2, e2p, ND, nullptr, ND, NHID / 2, NHID,
      (size_t)MAXSLOT * ND, chunk_e, nullptr);
  combine_kernel<<<dim3(NTOK), 256, 0, stream>>>(e2p, slot_of, rwt, h_f, attn_x, moe_g, moe_b,
                                                 (float*)d_out);
}

// Round 9
// 517.174 us; speedup vs baseline: 1.4614x; 1.0395x over previous
//
#include <hip/hip_runtime.h>
#include <hip/hip_bf16.h>
#include <stdint.h>

using bf16 = __hip_bfloat16;
typedef short s16x8 __attribute__((ext_vector_type(8)));
typedef float f32x4 __attribute__((ext_vector_type(4)));

#define NB 4
#define NS 1024
#define ND 768
#define NH 12
#define NE 8
#define NHID 3072
#define NTOK 4096
#define NASSIGN 8192
#define MAXCH 72               // sum ceil(counts[e]/128) <= 64 + 8
#define MAXSLOT (MAXCH * 128)  // 9216

__device__ __forceinline__ float bf2f(bf16 v){ return __bfloat162float(v); }
__device__ __forceinline__ bf16 f2bf(float v){ return __float2bfloat16(v); }

__device__ __forceinline__ void gload_lds16(const bf16* g, bf16* l){
  __builtin_amdgcn_global_load_lds((const __attribute__((address_space(1))) void*)g,
                                   (__attribute__((address_space(3))) void*)l, 16, 0, 0);
}

// ---------------- transpose + fp32->bf16 convert, 64x64 tile, 16B loads/stores
__device__ __forceinline__ void transpose64_body(const float* __restrict__ src,
                                                 bf16* __restrict__ dst,
                                                 int K, int N, int n0, int k0, int t){
  __shared__ float tile[64][65];
  int kr = t >> 4, c4 = (t & 15) * 4;
  #pragma unroll
  for (int i = 0; i < 4; i++){
    int k = kr + i * 16;
    float4 v = *(const float4*)(src + (size_t)(k0 + k) * N + n0 + c4);
    tile[k][c4]     = v.x;
    tile[k][c4 + 1] = v.y;
    tile[k][c4 + 2] = v.z;
    tile[k][c4 + 3] = v.w;
  }
  __syncthreads();
  int nr = t >> 3, k8 = (t & 7) * 8;
  #pragma unroll
  for (int i = 0; i < 2; i++){
    int n = nr + i * 32;
    short vv[8];
    #pragma unroll
    for (int j = 0; j < 8; j++){
      bf16 x = f2bf(tile[k8 + j][n]);
      vv[j] = *(short*)&x;
    }
    *(s16x8*)(dst + (size_t)(n0 + n) * K + k0 + k8) = *(s16x8*)vv;
  }
}

__global__ void transpose_convert_kernel(const float* __restrict__ src, bf16* __restrict__ dst,
                                         int K, int N){
  int bz = blockIdx.z;
  transpose64_body(src + (size_t)bz * K * N, dst + (size_t)bz * N * K,
                   K, N, blockIdx.x * 64, blockIdx.y * 64, threadIdx.x);
}

// four 768x768 fp32->bf16 transposes in one dispatch (wq,wk,wv,wo -> contiguous dst)
struct Ptr4 { const float* p0; const float* p1; const float* p2; const float* p3; };
__global__ void transpose4_kernel(Ptr4 s4, bf16* __restrict__ dst){
  int z = blockIdx.z;
  const float* src = (z == 0) ? s4.p0 : (z == 1) ? s4.p1 : (z == 2) ? s4.p2 : s4.p3;
  transpose64_body(src, dst + (size_t)z * 768 * 768,
                   768, 768, blockIdx.x * 64, blockIdx.y * 64, threadIdx.x);
}

// ---------------- concat 3 bias vectors [768] -> [2304]
__global__ void concat3_kernel(const float* __restrict__ a, const float* __restrict__ b,
                               const float* __restrict__ c, float* __restrict__ out){
  int i = blockIdx.x * 256 + threadIdx.x;
  if (i >= 3 * ND) return;
  float v = (i < ND) ? a[i] : (i < 2 * ND ? b[i - ND] : c[i - 2 * ND]);
  out[i] = v;
}

// ---------------- LayerNorm row kernel (768 per row, 256 threads)
template<bool OF, bool OB>
__global__ void ln_kernel(const float* __restrict__ in, const float* __restrict__ g,
                          const float* __restrict__ bb, float* __restrict__ of,
                          bf16* __restrict__ ob){
  int row = blockIdx.x, t = threadIdx.x;
  const float* x = in + (size_t)row * ND;
  float v[3]; float s = 0.f, sq = 0.f;
  #pragma unroll
  for (int i = 0; i < 3; i++){ v[i] = x[t + i * 256]; s += v[i]; sq += v[i] * v[i]; }
  __shared__ float rs[4], rq[4];
  #pragma unroll
  for (int d = 32; d >= 1; d >>= 1){ s += __shfl_xor(s, d); sq += __shfl_xor(sq, d); }
  int w = t >> 6;
  if ((t & 63) == 0){ rs[w] = s; rq[w] = sq; }
  __syncthreads();
  s = rs[0] + rs[1] + rs[2] + rs[3];
  sq = rq[0] + rq[1] + rq[2] + rq[3];
  float mean = s * (1.f / ND);
  float var = sq * (1.f / ND) - mean * mean;
  float rstd = rsqrtf(var + 1e-5f);
  #pragma unroll
  for (int i = 0; i < 3; i++){
    int idx = t + i * 256;
    float y = (v[i] - mean) * rstd * g[idx] + bb[idx];
    if (OF) of[(size_t)row * ND + idx] = y;
    if (OB) ob[(size_t)row * ND + idx] = f2bf(y);
  }
}

// ---------------- GEMM: C[chunk rows][N] = A @ Bt^T + bias
// SPLITZ (e2): xcd owns 18 CONTIGUOUS (chunk,ks) groups (same-expert runs ->
//   B-half stays L2-hot across chunks); nt fast within group (A panel shared).
// XMAJ (e1): xcd owns 9 contiguous chunks; chunk FAST, nt SLOW -> concurrent
//   working set = 9 A panels (1.8MB, resident) + ~8 transient B panels (1.6MB)
//   < 4MB L2. (Previous nt-fast decode held 24 B panels = 4.7MB -> thrash.)
template<int GROUP, bool GATHER, bool RELU, bool OBF, bool RESID, bool SEG, bool SPLITZ, bool XMAJ>
__global__ __launch_bounds__(256, 4)
void gemm_kernel(const bf16* __restrict__ A, int ldA,
                 const bf16* __restrict__ BtB,
                 const float* __restrict__ biasB,
                 void* __restrict__ Cv, int ldC,
                 const float* __restrict__ resid,
                 int N, int K, int ldB, size_t czstride,
                 const int* __restrict__ chunk_e, const int* __restrict__ tok){
  __shared__ __align__(16) bf16 sA[2][128 * 32];
  __shared__ __align__(16) bf16 sB[2][128 * 32];

  int t = threadIdx.x;
  int lane = t & 63, wv = t >> 6;
  int c0i = wv * 128 + lane;          // staging chunk id (and c0i+64)
  int r0  = c0i >> 2;                 // tile-local row of chunk0; chunk1 row = r0+16
  int kk  = (c0i & 3) * 8;
  int nt, cbase = 0, ks = 0;
  if (SPLITZ){
    int l = blockIdx.x, xcd = l & 7, slot = l >> 3;   // slot 0..107
    int grp = xcd * 18 + slot / 6;    // contiguous (chunk,ks) groups per XCD
    nt = slot % 6;                    // A panel shared by the 6 concurrent nt
    cbase = grp % MAXCH;
    ks = grp / MAXCH;
  } else if (XMAJ){
    int l = blockIdx.x, xcd = l & 7, slot = l >> 3;   // slot 0..215
    cbase = xcd * 9 + slot % 9;       // chunk FAST
    nt = slot / 9;                    // nt SLOW
  } else {
    nt = blockIdx.x;
  }
  int koff = ks * K;
  float* Cfs = (float*)Cv + (size_t)ks * czstride;
  int wm = (wv >> 1) * 64, wn = (wv & 1) * 64;
  int l16 = lane & 15, q4 = lane >> 4;
  int aoff[4], boff[4];
  #pragma unroll
  for (int mi = 0; mi < 4; mi++) aoff[mi] = (wm + mi * 16 + l16) * 32 + q4 * 8;
  #pragma unroll
  for (int ni = 0; ni < 4; ni++) boff[ni] = (wn + ni * 16 + l16) * 32 + q4 * 8;

  for (int g = 0; g < GROUP; g++){
    int c = (SPLITZ || XMAJ) ? cbase : blockIdx.y * GROUP + g;
    int e = 0;
    if (SEG){ e = chunk_e[c]; if (e < 0) break; }
    const bf16* Bt = SEG ? BtB + (size_t)e * N * ldB : BtB;
    const float* bias = SEG ? biasB + (size_t)e * N : biasB;
    size_t arow0, arow1;
    int m0 = c * 128 + r0, m1 = m0 + 16;
    if (GATHER){ arow0 = (size_t)tok[m0]; arow1 = (size_t)tok[m1]; }
    else       { arow0 = (size_t)m0;      arow1 = (size_t)m1; }
    const bf16* gA0 = A + arow0 * ldA + koff + kk;
    const bf16* gA1 = A + arow1 * ldA + koff + kk;
    const bf16* gB0 = Bt + (size_t)(nt * 128 + r0) * ldB + koff + kk;
    const bf16* gB1 = Bt + (size_t)(nt * 128 + r0 + 16) * ldB + koff + kk;

    if (g > 0) __syncthreads();  // protect LDS reuse across chunks

    f32x4 acc[4][4] = {};
    gload_lds16(gA0, &sA[0][(size_t)c0i * 8]);
    gload_lds16(gA1, &sA[0][(size_t)(c0i + 64) * 8]);
    gload_lds16(gB0, &sB[0][(size_t)c0i * 8]);
    gload_lds16(gB1, &sB[0][(size_t)(c0i + 64) * 8]);

    int nk = K >> 5;
    for (int ki = 0; ki < nk; ki++){
      int cur = ki & 1;
      __syncthreads();
      if (ki + 1 < nk){
        int nxt = cur ^ 1, off = (ki + 1) * 32;
        gload_lds16(gA0 + off, &sA[nxt][(size_t)c0i * 8]);
        gload_lds16(gA1 + off, &sA[nxt][(size_t)(c0i + 64) * 8]);
        gload_lds16(gB0 + off, &sB[nxt][(size_t)c0i * 8]);
        gload_lds16(gB1 + off, &sB[nxt][(size_t)(c0i + 64) * 8]);
      }
      s16x8 af[4], bfr[4];
      #pragma unroll
      for (int mi = 0; mi < 4; mi++) af[mi] = *(const s16x8*)(&sA[cur][0] + aoff[mi]);
      #pragma unroll
      for (int ni = 0; ni < 4; ni++) bfr[ni] = *(const s16x8*)(&sB[cur][0] + boff[ni]);
      #pragma unroll
      for (int mi = 0; mi < 4; mi++)
        #pragma unroll
        for (int ni = 0; ni < 4; ni++)
          acc[mi][ni] = __builtin_amdgcn_mfma_f32_16x16x32_bf16(af[mi], bfr[ni], acc[mi][ni], 0, 0, 0);
    }

    #pragma unroll
    for (int mi = 0; mi < 4; mi++){
      #pragma unroll
      for (int ni = 0; ni < 4; ni++){
        int col = nt * 128 + wn + ni * 16 + l16;
        float bv = (!SPLITZ || ks == 0) ? bias[col] : 0.f;
        #pragma unroll
        for (int r = 0; r < 4; r++){
          size_t crow = (size_t)(c * 128 + wm + mi * 16 + q4 * 4 + r);
          float v = acc[mi][ni][r] + bv;
          if (RELU) v = fmaxf(v, 0.f);
          if (RESID) v += resid[crow * ldC + col];
          if (OBF) ((bf16*)Cv)[crow * ldC + col] = f2bf(v);
          else     Cfs[crow * ldC + col] = v;
        }
      }
    }
  }
}

// ---------------- V transpose: qkv v-cols [b,s,h,d] -> vT [b,h,d,s] (bf16)
__global__ void vtrans_kernel(const bf16* __restrict__ qkv, bf16* __restrict__ vT){
  __shared__ bf16 tile[64][65];
  int bh = blockIdx.z; int b = bh / NH, h = bh % NH;
  int s0 = blockIdx.x * 64;
  int t = threadIdx.x;
  int sr = t >> 3, d8 = (t & 7) * 8;
  #pragma unroll
  for (int i = 0; i < 2; i++){
    int s = sr + i * 32;
    s16x8 v = *(const s16x8*)(qkv + (size_t)(b * NS + s0 + s) * 2304 + 1536 + h * 64 + d8);
    #pragma unroll
    for (int j = 0; j < 8; j++) tile[d8 + j][s] = ((bf16*)&v)[j];
  }
  __syncthreads();
  int dr = t >> 3, s8 = (t & 7) * 8;
  #pragma unroll
  for (int i = 0; i < 2; i++){
    int d = dr + i * 32;
    short vv[8];
    #pragma unroll
    for (int j = 0; j < 8; j++){ bf16 x = tile[d][s8 + j]; vv[j] = *(short*)&x; }
    *(s16x8*)(vT + ((size_t)bh * 64 + d) * NS + s0 + s8) = *(s16x8*)vv;
  }
}

// ---------------- flash attention v3 (unchanged)
#define SPAD 72
__global__ __launch_bounds__(256, 3)
void flash_attn_kernel(const bf16* __restrict__ qkv, const bf16* __restrict__ vT,
                       bf16* __restrict__ ctx){
  __shared__ __align__(16) bf16 sK[2][64 * 64];
  __shared__ __align__(16) bf16 sV[2][64 * 64];
  __shared__ __align__(16) bf16 sP[4][16 * SPAD];
  int id = blockIdx.x;
  int bh = id % 48;
  int qt = 15 - (id / 48);
  int b = bh / NH, h = bh % NH;
  int t = threadIdx.x, lane = t & 63, wv = t >> 6;
  int l16 = lane & 15, q4 = lane >> 4;
  int q0 = qt * 64 + wv * 16;
  const size_t ldq = 2304;
  const bf16* qbase = qkv + (size_t)(b * NS) * ldq + h * 64;
  const bf16* kbase = qbase + 768;
  const bf16* vtb = vT + (size_t)bh * 64 * NS;
  bf16* sPw = &sP[wv][0];
  const f32x4 fzero = {0.f, 0.f, 0.f, 0.f};

  s16x8 qf[2];
  #pragma unroll
  for (int kh = 0; kh < 2; kh++)
    qf[kh] = *(const s16x8*)(qbase + (size_t)(q0 + l16) * ldq + kh * 32 + q4 * 8);

  f32x4 O[4] = {};
  float ms[4], ls[4];
  #pragma unroll
  for (int r = 0; r < 4; r++){ ms[r] = -1e30f; ls[r] = 0.f; }

  int sub = lane >> 3, rawc = lane & 7;
  auto stage = [&](int buf, int key0){
    #pragma unroll
    for (int i = 0; i < 2; i++){
      int rk = wv * 8 + sub + i * 32;          // key row (K) / dh row (V)
      int cs = (rawc ^ (rk & 7)) * 8;          // swizzled source col (elems)
      gload_lds16(kbase + (size_t)(key0 + rk) * ldq + cs, &sK[buf][wv * 512 + i * 2048]);
      gload_lds16(vtb + (size_t)rk * NS + key0 + cs,      &sV[buf][wv * 512 + i * 2048]);
    }
  };

  int ntiles = qt + 1;
  stage(0, 0);
  for (int ti = 0; ti < ntiles; ti++){
    int cur = ti & 1, key0 = ti * 64;
    __syncthreads();                       // drains own staging loads + barrier
    if (ti + 1 < ntiles) stage(cur ^ 1, (ti + 1) * 64);
    if (key0 <= q0 + 15){
      const bf16* sKc = &sK[cur][0];
      const bf16* sVc = &sV[cur][0];
      s16x8 kf[4][2], vf[4][2];
      #pragma unroll
      for (int ni = 0; ni < 4; ni++){
        int krow = ni * 16 + l16;
        #pragma unroll
        for (int kh = 0; kh < 2; kh++)
          kf[ni][kh] = *(const s16x8*)(sKc + krow * 64 + (((kh * 4 + q4) ^ (krow & 7)) * 8));
      }
      #pragma unroll
      for (int dt = 0; dt < 4; dt++){
        int vrow = dt * 16 + l16;
        #pragma unroll
        for (int kh = 0; kh < 2; kh++)
          vf[dt][kh] = *(const s16x8*)(sVc + vrow * 64 + (((kh * 4 + q4) ^ (vrow & 7)) * 8));
      }
      f32x4 Sf[4];
      #pragma unroll
      for (int ni = 0; ni < 4; ni++){
        Sf[ni] = __builtin_amdgcn_mfma_f32_16x16x32_bf16(qf[0], kf[ni][0], fzero, 0, 0, 0);
        Sf[ni] = __builtin_amdgcn_mfma_f32_16x16x32_bf16(qf[1], kf[ni][1], Sf[ni], 0, 0, 0);
      }
      bool need_mask = (key0 + 63 >= q0);  // wave-uniform
      #pragma unroll
      for (int r = 0; r < 4; r++){
        int qrow = q0 + q4 * 4 + r;
        float sv[4];
        #pragma unroll
        for (int ni = 0; ni < 4; ni++){
          sv[ni] = Sf[ni][r] * 0.125f;
          if (need_mask && (key0 + ni * 16 + l16 > qrow)) sv[ni] = -1e30f;
        }
        float mx = fmaxf(fmaxf(sv[0], sv[1]), fmaxf(sv[2], sv[3]));
        #pragma unroll
        for (int d = 8; d >= 1; d >>= 1) mx = fmaxf(mx, __shfl_xor(mx, d));
        float mnew = fmaxf(ms[r], mx);
        float alpha = __expf(ms[r] - mnew);
        float p[4], psum = 0.f;
        #pragma unroll
        for (int ni = 0; ni < 4; ni++){ p[ni] = __expf(sv[ni] - mnew); psum += p[ni]; }
        #pragma unroll
        for (int d = 8; d >= 1; d >>= 1) psum += __shfl_xor(psum, d);
        ls[r] = ls[r] * alpha + psum;
        ms[r] = mnew;
        #pragma unroll
        for (int dt = 0; dt < 4; dt++) O[dt][r] *= alpha;
        int prow = q4 * 4 + r;
        #pragma unroll
        for (int ni = 0; ni < 4; ni++)
          sPw[prow * SPAD + ni * 16 + l16] = f2bf(p[ni]);
      }
      s16x8 pf[2];
      #pragma unroll
      for (int kh = 0; kh < 2; kh++)
        pf[kh] = *(const s16x8*)(sPw + l16 * SPAD + kh * 32 + q4 * 8);
      #pragma unroll
      for (int dt = 0; dt < 4; dt++){
        O[dt] = __builtin_amdgcn_mfma_f32_16x16x32_bf16(pf[0], vf[dt][0], O[dt], 0, 0, 0);
        O[dt] = __builtin_amdgcn_mfma_f32_16x16x32_bf16(pf[1], vf[dt][1], O[dt], 0, 0, 0);
      }
    }
  }

  #pragma unroll
  for (int r = 0; r < 4; r++){
    float inv = 1.f / ls[r];
    int qrow = q0 + q4 * 4 + r;
    #pragma unroll
    for (int dt = 0; dt < 4; dt++)
      ctx[(size_t)(b * NS + qrow) * ND + h * 64 + dt * 16 + l16] = f2bf(O[dt][r] * inv);
  }
}

// ---------------- gate v2: 128 blocks x 32 tokens; LDS count aggregation
__global__ __launch_bounds__(256)
void gate_kernel(const float* __restrict__ h, const float* __restrict__ gw,
                 const float* __restrict__ gb, int* __restrict__ ridx,
                 float* __restrict__ rw, int* __restrict__ counts){
  __shared__ float sgw[NE * ND];   // transposed: sgw[e*ND+i] -> stride-1 reads
  __shared__ int scnt[NE];
  int t = threadIdx.x;
  if (t < NE) scnt[t] = 0;
  for (int idx = t; idx < ND * NE; idx += 256){
    int i = idx >> 3, e = idx & 7;
    sgw[e * ND + i] = gw[idx];
  }
  __syncthreads();
  int lane = t & 63, wv = t >> 6;
  for (int it = 0; it < 8; it++){
    int tok = blockIdx.x * 32 + it * 4 + wv;
    const float* hr = h + (size_t)tok * ND;
    float acc[NE] = {};
    #pragma unroll
    for (int ii = 0; ii < 12; ii++){
      int i = lane + ii * 64;
      float hv = hr[i];
      #pragma unroll
      for (int e = 0; e < NE; e++) acc[e] += hv * sgw[e * ND + i];
    }
    #pragma unroll
    for (int e = 0; e < NE; e++)
      #pragma unroll
      for (int d = 32; d >= 1; d >>= 1) acc[e] += __shfl_xor(acc[e], d);
    if (lane == 0){
      float v0 = -1e30f, v1 = -1e30f; int i0 = 0, i1 = 0;
      #pragma unroll
      for (int e = 0; e < NE; e++){
        float v = acc[e] + gb[e];
        if (v > v0){ v1 = v0; i1 = i0; v0 = v; i0 = e; }
        else if (v > v1){ v1 = v; i1 = e; }
      }
      float w0 = 1.f / (1.f + __expf(v1 - v0));
      ridx[tok * 2] = i0; ridx[tok * 2 + 1] = i1;
      rw[tok * 2] = w0;  rw[tok * 2 + 1] = 1.f - w0;
      atomicAdd(&scnt[i0], 1);
      atomicAdd(&scnt[i1], 1);
    }
  }
  __syncthreads();
  if (t < NE) atomicAdd(&counts[t], scnt[t]);
}

// scan: padded (128-aligned) expert offsets + chunk->expert map + tok_list prefill
__global__ void scan_kernel(const int* __restrict__ counts, int* __restrict__ poff,
                            int* __restrict__ chunk_e, int* __restrict__ tok_list){
  int t = threadIdx.x;
  for (int i = t; i < MAXSLOT; i += 256) tok_list[i] = 0;
  if (t == 0){
    int s = 0, c = 0;
    for (int e = 0; e < NE; e++){
      poff[e] = s;
      int nch = (counts[e] + 127) >> 7;
      for (int i = 0; i < nch; i++) chunk_e[c++] = e;
      s += nch << 7;
    }
    for (; c < MAXCH; c++) chunk_e[c] = -1;
  }
}

// scatter v2: wave-aggregated atomics (1 atomic per expert per wave)
__global__ void scatter_kernel(const int* __restrict__ ridx, const int* __restrict__ poff,
                               int* __restrict__ cursor, int* __restrict__ tok_list,
                               int* __restrict__ slot_of){
  int tk = blockIdx.x * 256 + threadIdx.x;
  int lane = threadIdx.x & 63;
  int e = ridx[tk];
  unsigned long long lmask = (1ull << lane) - 1;  // bits below lane
  int slot = 0;
  #pragma unroll
  for (int ee = 0; ee < NE; ee++){
    unsigned long long mask = __ballot(e == ee);
    if (mask == 0ull) continue;
    int leader = __ffsll((unsigned long long)mask) - 1;
    int base = 0;
    if (lane == leader) base = atomicAdd(&cursor[ee], __popcll(mask));
    base = __shfl(base, leader);
    if (e == ee) slot = poff[ee] + base + __popcll(mask & lmask);
  }
  tok_list[slot] = tk >> 1;
  slot_of[tk] = slot;
}

// ---------------- combine: core = w0*(p0[s0]+p1[s0]) + w1*(p0[s1]+p1[s1]);
// out = attn_x + LN(h+core).  e2 partials are fp32 (split-K halves).
__global__ void combine_kernel(const float* __restrict__ e2p, const int* __restrict__ slot_of,
                               const float* __restrict__ rw, const float* __restrict__ hf,
                               const float* __restrict__ attn_x, const float* __restrict__ g,
                               const float* __restrict__ bb, float* __restrict__ out){
  int row = blockIdx.x, t = threadIdx.x;
  int sl0 = slot_of[row * 2], sl1 = slot_of[row * 2 + 1];
  float w0 = rw[row * 2], w1 = rw[row * 2 + 1];
  const float* r0a = e2p + (size_t)sl0 * ND;
  const float* r0b = r0a + (size_t)MAXSLOT * ND;
  const float* r1a = e2p + (size_t)sl1 * ND;
  const float* r1b = r1a + (size_t)MAXSLOT * ND;
  const float* hr = hf + (size_t)row * ND;
  float v[3]; float s = 0.f, sq = 0.f;
  #pragma unroll
  for (int i = 0; i < 3; i++){
    int idx = t + i * 256;
    float c = w0 * (r0a[idx] + r0b[idx]) + w1 * (r1a[idx] + r1b[idx]);
    float xv = hr[idx] + c;
    v[i] = xv; s += xv; sq += xv * xv;
  }
  __shared__ float rs[4], rq[4];
  #pragma unroll
  for (int d = 32; d >= 1; d >>= 1){ s += __shfl_xor(s, d); sq += __shfl_xor(sq, d); }
  int w = t >> 6;
  if ((t & 63) == 0){ rs[w] = s; rq[w] = sq; }
  __syncthreads();
  s = rs[0] + rs[1] + rs[2] + rs[3];
  sq = rq[0] + rq[1] + rq[2] + rq[3];
  float mean = s * (1.f / ND);
  float var = sq * (1.f / ND) - mean * mean;
  float rstd = rsqrtf(var + 1e-5f);
  #pragma unroll
  for (int i = 0; i < 3; i++){
    int idx = t + i * 256;
    float y = (v[i] - mean) * rstd * g[idx] + bb[idx];
    out[(size_t)row * ND + idx] = attn_x[(size_t)row * ND + idx] + y;
  }
}

// ================= host =================
extern "C" void kernel_launch(void* const* d_in, const int* in_sizes, int n_in,
                              void* d_out, int out_size, void* d_ws, size_t ws_size,
                              hipStream_t stream){
  const float* x        = (const float*)d_in[0];
  const float* ln_att_g = (const float*)d_in[2];
  const float* ln_att_b = (const float*)d_in[3];
  const float* wq = (const float*)d_in[4];  const float* bq = (const float*)d_in[5];
  const float* wk = (const float*)d_in[6];  const float* bk = (const float*)d_in[7];
  const float* wv = (const float*)d_in[8];  const float* bv = (const float*)d_in[9];
  const float* wo = (const float*)d_in[10]; const float* bo = (const float*)d_in[11];
  const float* ln_ff_g = (const float*)d_in[12];
  const float* ln_ff_b = (const float*)d_in[13];
  const float* gate_w  = (const float*)d_in[14];
  const float* gate_b  = (const float*)d_in[15];
  const float* w1 = (const float*)d_in[16]; const float* b1 = (const float*)d_in[17];
  const float* w2 = (const float*)d_in[18]; const float* b2 = (const float*)d_in[19];
  const float* moe_g = (const float*)d_in[20];
  const float* moe_b = (const float*)d_in[21];

  uint8_t* p = (uint8_t*)d_ws;
  auto alloc = [&](size_t bytes) -> void* {
    void* r = (void*)p;
    p += (bytes + 255) & ~(size_t)255;
    return r;
  };
  // wqkv_t (2304x768) and wo_t (768x768) contiguous: one transpose4 dispatch
  bf16* wqkv_t  = (bf16*)alloc((size_t)(2304 + 768) * 768 * 2);
  bf16* wo_t    = wqkv_t + (size_t)2304 * 768;
  bf16* w1_t    = (bf16*)alloc((size_t)NE * NHID * ND * 2);
  bf16* w2_t    = (bf16*)alloc((size_t)NE * ND * NHID * 2);
  float* bias_qkv = (float*)alloc(2304 * 4);
  bf16* a_bf    = (bf16*)alloc((size_t)NTOK * ND * 2);
  bf16* qkv     = (bf16*)alloc((size_t)NTOK * 2304 * 2);
  bf16* vT      = (bf16*)alloc((size_t)NB * NH * 64 * NS * 2);
  bf16* ctx     = (bf16*)alloc((size_t)NTOK * ND * 2);
  float* attn_x = (float*)alloc((size_t)NTOK * ND * 4);
  float* h_f    = (float*)alloc((size_t)NTOK * ND * 4);
  bf16* h_b     = (bf16*)alloc((size_t)NTOK * ND * 2);
  int*  ridx    = (int*)alloc(NASSIGN * 4);
  float* rwt    = (float*)alloc(NASSIGN * 4);
  int* counts   = (int*)alloc(NE * 4);
  int* poff     = (int*)alloc(NE * 4);
  int* cursor   = (int*)alloc(NE * 4);
  int* chunk_e  = (int*)alloc(MAXCH * 4);
  int* tok_list = (int*)alloc(MAXSLOT * 4);
  int* slot_of  = (int*)alloc(NASSIGN * 4);
  bf16* e1      = (bf16*)alloc((size_t)MAXSLOT * NHID * 2);
  float* e2p    = (float*)alloc((size_t)2 * MAXSLOT * ND * 4);  // split-K fp32 partials

  hipMemsetAsync(counts, 0, NE * 4, stream);
  hipMemsetAsync(cursor, 0, NE * 4, stream);

  // weight prep: one batched dispatch for wq/wk/wv/wo, one each for w1/w2
  Ptr4 s4; s4.p0 = wq; s4.p1 = wk; s4.p2 = wv; s4.p3 = wo;
  transpose4_kernel<<<dim3(12, 12, 4), 256, 0, stream>>>(s4, wqkv_t);
  transpose_convert_kernel<<<dim3(48, 12, NE), 256, 0, stream>>>(w1, w1_t, 768, 3072);
  transpose_convert_kernel<<<dim3(12, 48, NE), 256, 0, stream>>>(w2, w2_t, 3072, 768);
  concat3_kernel<<<dim3(9), 256, 0, stream>>>(bq, bk, bv, bias_qkv);

  // attention path
  ln_kernel<false, true><<<dim3(NTOK), 256, 0, stream>>>(x, ln_att_g, ln_att_b, nullptr, a_bf);
  gemm_kernel<1, false, false, true, false, false, false, false><<<dim3(18, 32), 256, 0, stream>>>(
      a_bf, ND, wqkv_t, bias_qkv, qkv, 2304, nullptr, 2304, ND, ND, 0, nullptr, nullptr);
  vtrans_kernel<<<dim3(16, 1, NB * NH), 256, 0, stream>>>(qkv, vT);
  flash_attn_kernel<<<dim3(768), 256, 0, stream>>>(qkv, vT, ctx);
  gemm_kernel<1, false, false, false, true, false, false, false><<<dim3(6, 32), 256, 0, stream>>>(
      ctx, ND, wo_t, bo, attn_x, ND, x, ND, ND, ND, 0, nullptr, nullptr);

  // MoE path
  ln_kernel<true, true><<<dim3(NTOK), 256, 0, stream>>>(attn_x, ln_ff_g, ln_ff_b, h_f, h_b);
  gate_kernel<<<dim3(NTOK / 32), 256, 0, stream>>>(h_f, gate_w, gate_b, ridx, rwt, counts);
  scan_kernel<<<dim3(1), 256, 0, stream>>>(counts, poff, chunk_e, tok_list);
  scatter_kernel<<<dim3(NASSIGN / 256), 256, 0, stream>>>(ridx, poff, cursor, tok_list, slot_of);
  // e1: flat 1728-block grid, XCD decode with chunk-fast/nt-slow (L2-fit working set)
  gemm_kernel<1, true, true, true, false, true, false, true><<<dim3(1728), 256, 0, stream>>>(
      h_b, ND, w1_t, b1, e1, NHID, nullptr, NHID, ND, ND, 0, chunk_e, tok_list);
  // e2: split-K=2, flat 864-block grid; contiguous-chunk groups per XCD
  gemm_kernel<1, false, false, false, false, true, true, false><<<dim3(864), 256, 0, stream>>>(
      e1, NHID, w2_t, b2, e2p, ND, nullptr, ND, NHID / 2, NHID,
      (size_t)MAXSLOT * ND, chunk_e, nullptr);
  combine_kernel<<<dim3(NTOK), 256, 0, stream>>>(e2p, slot_of, rwt, h_f, attn_x, moe_g, moe_b,
                                                 (float*)d_out);
}